// Round 1
// baseline (836.201 us; speedup 1.0000x reference)
//
#include <hip/hip_runtime.h>

#define B 8
#define N 20000
#define M 256
#define I 64
#define O 64

// ---------------- Stage 1: dtx[b][m][i] = sum_n D[b][n][m] * x[b][n][i]
// grid (SPLIT, B), block 256. Thread owns 4 m x 16 i accumulators.
#define SPLIT 100
#define CHUNK (N / SPLIT)   // 200, divisible by 4

__global__ __launch_bounds__(256) void stage1(const float* __restrict__ Dg,
                                              const float* __restrict__ xg,
                                              float* __restrict__ dtx) {
    const int b = blockIdx.y;
    const int n0 = blockIdx.x * CHUNK;
    const int tid = threadIdx.x;
    const int m_base = (tid & 63) * 4;
    const int i_base = (tid >> 6) * 16;

    __shared__ float ldsD[4][M];
    __shared__ float ldsX[4][I];

    float acc[4][16];
#pragma unroll
    for (int a = 0; a < 4; ++a)
#pragma unroll
        for (int c = 0; c < 16; ++c) acc[a][c] = 0.f;

    const float* Dbase = Dg + (size_t)b * N * M;
    const float* xbase = xg + (size_t)b * N * I;

    for (int nt = 0; nt < CHUNK; nt += 4) {
        // stage 4 D rows (1024 floats) + 4 x rows (256 floats)
        {
            const int r = tid >> 6;          // 0..3
            const int c = (tid & 63) * 4;    // 0..252
            *(float4*)&ldsD[r][c] =
                *(const float4*)&Dbase[(size_t)(n0 + nt + r) * M + c];
            ldsX[r][tid & 63] = xbase[(size_t)(n0 + nt + r) * I + (tid & 63)];
        }
        __syncthreads();
#pragma unroll
        for (int nn = 0; nn < 4; ++nn) {
            float4 d4 = *(const float4*)&ldsD[nn][m_base];
            float xv[16];
            *(float4*)&xv[0]  = *(const float4*)&ldsX[nn][i_base + 0];
            *(float4*)&xv[4]  = *(const float4*)&ldsX[nn][i_base + 4];
            *(float4*)&xv[8]  = *(const float4*)&ldsX[nn][i_base + 8];
            *(float4*)&xv[12] = *(const float4*)&ldsX[nn][i_base + 12];
            const float dm[4] = {d4.x, d4.y, d4.z, d4.w};
#pragma unroll
            for (int a = 0; a < 4; ++a)
#pragma unroll
                for (int c = 0; c < 16; ++c)
                    acc[a][c] = fmaf(dm[a], xv[c], acc[a][c]);
        }
        __syncthreads();
    }

    float* outp = dtx + (size_t)b * M * I;
#pragma unroll
    for (int a = 0; a < 4; ++a)
#pragma unroll
        for (int c = 0; c < 16; ++c)
            atomicAdd(&outp[(size_t)(m_base + a) * I + i_base + c], acc[a][c]);
}

// ---------------- Stage 2: S[b][m][o] = (1/16) * sum_i coeff[o][i][m] * dtx[b][m][i]
__global__ __launch_bounds__(256) void stage2(const float* __restrict__ coeff,
                                              const float* __restrict__ dtx,
                                              float* __restrict__ S) {
    const int g = blockIdx.x * 256 + threadIdx.x;   // 0 .. B*O*M-1
    const int b = g >> 14;            // O*M = 16384
    const int rem = g & 16383;
    const int o = rem >> 8;
    const int m = rem & 255;
    const float* dt = dtx + (size_t)b * M * I + (size_t)m * I;
    const float* cf = coeff + (size_t)o * I * M + m;
    float acc = 0.f;
#pragma unroll 8
    for (int i = 0; i < I; ++i)
        acc = fmaf(cf[(size_t)i * M], dt[i], acc);
    S[(size_t)b * M * O + (size_t)m * O + o] = acc * 0.0625f;   // 1/sqrt(256)
}

// ---------------- Stage 3: out[b][n][o] = sum_m D[b][n][m] * S[b][m][o]
#define MC 32
#define NTILE 64
#define NBLK ((N + NTILE - 1) / NTILE)   // 313

__global__ __launch_bounds__(256) void stage3(const float* __restrict__ Dg,
                                              const float* __restrict__ Sg,
                                              float* __restrict__ outg) {
    const int b = blockIdx.y;
    const int n0 = blockIdx.x * NTILE;
    const int tid = threadIdx.x;
    const int nl = tid & 63;
    const int o_base = (tid >> 6) * 16;

    __shared__ float Dt[NTILE][MC + 1];   // [n][m], stride 33 -> 2-way max
    __shared__ float St[MC][O];           // [m][o]

    float acc[16];
#pragma unroll
    for (int j = 0; j < 16; ++j) acc[j] = 0.f;

    const float* Db = Dg + (size_t)b * N * M;
    const float* Sb = Sg + (size_t)b * M * O;

    for (int mc = 0; mc < M; mc += MC) {
#pragma unroll
        for (int r = 0; r < 2; ++r) {
            const int f = tid + r * 256;       // 0..511 float4 slots
            const int n_row = f >> 3;          // 0..63
            const int m_off = (f & 7) * 4;     // 0..28
            const int gn = min(n0 + n_row, N - 1);
            float4 d4 = *(const float4*)&Db[(size_t)gn * M + mc + m_off];
            Dt[n_row][m_off + 0] = d4.x;
            Dt[n_row][m_off + 1] = d4.y;
            Dt[n_row][m_off + 2] = d4.z;
            Dt[n_row][m_off + 3] = d4.w;
            // S chunk: contiguous copy of 2048 floats
            *(float4*)((float*)St + (size_t)f * 4) =
                *(const float4*)&Sb[(size_t)mc * O + (size_t)f * 4];
        }
        __syncthreads();
#pragma unroll
        for (int mm = 0; mm < MC; ++mm) {
            const float d = Dt[nl][mm];
            float sv[16];
            *(float4*)&sv[0]  = *(const float4*)&St[mm][o_base + 0];
            *(float4*)&sv[4]  = *(const float4*)&St[mm][o_base + 4];
            *(float4*)&sv[8]  = *(const float4*)&St[mm][o_base + 8];
            *(float4*)&sv[12] = *(const float4*)&St[mm][o_base + 12];
#pragma unroll
            for (int j = 0; j < 16; ++j)
                acc[j] = fmaf(d, sv[j], acc[j]);
        }
        __syncthreads();
    }

    const int gn = n0 + nl;
    if (gn < N) {
        float* op = outg + ((size_t)b * N + gn) * O + o_base;
        *(float4*)&op[0]  = make_float4(acc[0],  acc[1],  acc[2],  acc[3]);
        *(float4*)&op[4]  = make_float4(acc[4],  acc[5],  acc[6],  acc[7]);
        *(float4*)&op[8]  = make_float4(acc[8],  acc[9],  acc[10], acc[11]);
        *(float4*)&op[12] = make_float4(acc[12], acc[13], acc[14], acc[15]);
    }
}

extern "C" void kernel_launch(void* const* d_in, const int* in_sizes, int n_in,
                              void* d_out, int out_size, void* d_ws, size_t ws_size,
                              hipStream_t stream) {
    const float* Dg    = (const float*)d_in[0];
    const float* xg    = (const float*)d_in[1];
    const float* coeff = (const float*)d_in[2];
    float* outg = (float*)d_out;

    float* dtx = (float*)d_ws;                       // B*M*I floats = 512 KB
    float* S   = dtx + (size_t)B * M * I;            // B*M*O floats = 512 KB

    hipMemsetAsync(dtx, 0, (size_t)B * M * I * sizeof(float), stream);
    stage1<<<dim3(SPLIT, B), 256, 0, stream>>>(Dg, xg, dtx);
    stage2<<<dim3((B * O * M) / 256), 256, 0, stream>>>(coeff, dtx, S);
    stage3<<<dim3(NBLK, B), 256, 0, stream>>>(Dg, S, outg);
}